// Round 16
// baseline (245.731 us; speedup 1.0000x reference)
//
#include <hip/hip_runtime.h>
#include <math.h>

#define DIM      1024
#define NSTRIPES 16     // fallback path only
#define PAD      4
#define MAXSLOTS 32
// Screen values are dot*inv_t = |src_row| * cos_sim (|src_row| ~ 32): bf16
// screen noise sigma ~= 1.6e-3 in SCREEN units; EPS = 0.08 ~= 35 sigma.
// Verified: rounds 5..15 passed with absmax 0 at this EPS. Guarantee is
// group-width independent (true argmax col's own group max >= its value).
#define EPS      0.08f

typedef __attribute__((ext_vector_type(8))) __bf16 bf16x8;
typedef __attribute__((ext_vector_type(4))) __bf16 bf16x4;
typedef __attribute__((ext_vector_type(4))) float f32x4;

#define FENCE() asm volatile("" ::: "memory")

__device__ __forceinline__ void async16(void* lds, const void* g) {
    __builtin_amdgcn_global_load_lds(
        (const __attribute__((address_space(1))) unsigned int*)g,
        (__attribute__((address_space(3))) unsigned int*)lds, 16, 0, 0);
}

// ---- fused: src f32->bf16; tgt f32->bf16 + inverse L2 norm (1 wave/row) ----
// (r14/r15-verified; tgt arithmetic bit-identical to r5..r13 convertB_norm)
__global__ void convert_all_kernel(const float* __restrict__ src,
                                   const float* __restrict__ tgt,
                                   unsigned short* __restrict__ bfA,
                                   unsigned short* __restrict__ bfB,
                                   float* __restrict__ inv_t, int M, int N) {
    int row = blockIdx.x * 4 + (threadIdx.x >> 6);
    int l = threadIdx.x & 63;
    if (row < M) {
        const float4* rp = (const float4*)(src + (size_t)row * DIM);
        unsigned short* wp = bfA + (size_t)row * DIM;
#pragma unroll
        for (int p = 0; p < 2; ++p) {
            int c = l + 64 * p;
            float4 v0 = rp[2 * c], v1 = rp[2 * c + 1];
            bf16x8 o;
            o[0] = (__bf16)v0.x; o[1] = (__bf16)v0.y;
            o[2] = (__bf16)v0.z; o[3] = (__bf16)v0.w;
            o[4] = (__bf16)v1.x; o[5] = (__bf16)v1.y;
            o[6] = (__bf16)v1.z; o[7] = (__bf16)v1.w;
            *(bf16x8*)(wp + (size_t)c * 8) = o;
        }
        return;
    }
    int trow = row - M;
    if (trow >= N) return;
    const float4* rp = (const float4*)(tgt + (size_t)trow * DIM);
    unsigned short* wp = bfB + (size_t)trow * DIM;
    float ss = 0.f;
#pragma unroll
    for (int p = 0; p < 4; ++p) {
        float4 v = rp[l + 64 * p];
        bf16x4 o;
        o[0] = (__bf16)v.x; o[1] = (__bf16)v.y;
        o[2] = (__bf16)v.z; o[3] = (__bf16)v.w;
        *(bf16x4*)(wp + (size_t)(l + 64 * p) * 4) = o;
        ss = fmaf(v.x, v.x, ss);
        ss = fmaf(v.y, v.y, ss);
        ss = fmaf(v.z, v.z, ss);
        ss = fmaf(v.w, v.w, ss);
    }
#pragma unroll
    for (int off = 32; off; off >>= 1) ss += __shfl_xor(ss, off, 64);
    if (l == 0) inv_t[trow] = 1.0f / fmaxf(sqrtf(ss), 1e-12f);
}

// ---- 256x256-tile bf16 MFMA screen, BK=64, ring-2, counted-vmcnt ----------
// r12 structure VERBATIM (proven 156us, absmax 0, 0 bank conflicts); only
// the epilogue is templated on GSH (group shift). GSH=2 (GW=4): a group is
// the 4 in-register r values at fixed q -> NO cross-lane reduce, all 64
// lanes write. GSH=3 (GW=8): r10-proven shfl-16 path.
template <int GSH>
__global__ __launch_bounds__(512) void mfma_argmax256_kernel(
    const unsigned short* __restrict__ Abf,
    const unsigned short* __restrict__ Bbf,
    const float* __restrict__ inv_t,
    float* __restrict__ sbest,   // [M][N>>GSH]
    int M, int N) {
    __shared__ __align__(16) unsigned short sA[2][16384];
    __shared__ __align__(16) unsigned short sB[2][16384];
    const int tid = threadIdx.x;
    const int w = tid >> 6, l = tid & 63;
    const int wr = w >> 2, wc = w & 3;   // 2 x 4 wave grid
    const int rowBase = blockIdx.x * 256;
    const int colBase = blockIdx.y * 256;
    const int ngroups = N >> GSH;
    const int NT = DIM / 64;

    int goff[4], lbase[4];
#pragma unroll
    for (int j = 0; j < 4; ++j) {
        int c = j * 512 + tid;
        int row = c >> 3, c8 = c & 7;
        goff[j] = row * DIM + (c8 ^ (row & 7)) * 8;  // ushort units
        lbase[j] = (j * 512 + w * 64) * 8;           // wave-uniform (ushort)
    }

    const int q = l >> 4;
    int aoff[8], boff[4];
#pragma unroll
    for (int m = 0; m < 8; ++m) {
        int row = wr * 128 + m * 16 + (l & 15);
        aoff[m] = (row * 128 + q * 16) ^ ((row & 7) << 4);
    }
#pragma unroll
    for (int n = 0; n < 4; ++n) {
        int col = wc * 64 + n * 16 + (l & 15);
        boff[n] = (col * 128 + q * 16) ^ ((col & 7) << 4);
    }

    f32x4 acc[8][4];
#pragma unroll
    for (int m = 0; m < 8; ++m)
#pragma unroll
        for (int n = 0; n < 4; ++n) acc[m][n] = (f32x4){0.f, 0.f, 0.f, 0.f};

    const unsigned short* ga = Abf + (size_t)rowBase * DIM;
    const unsigned short* gb = Bbf + (size_t)colBase * DIM;

    auto stage = [&](int t) {
        unsigned short* dA = &sA[t & 1][0];
        unsigned short* dB = &sB[t & 1][0];
#pragma unroll
        for (int j = 0; j < 4; ++j) {
            async16(dA + lbase[j], ga + t * 64 + goff[j]);
            async16(dB + lbase[j], gb + t * 64 + goff[j]);
        }
    };
    auto compute = [&](int i) {
        const char* bA = (const char*)&sA[i & 1][0];
        const char* bB = (const char*)&sB[i & 1][0];
#pragma unroll
        for (int s = 0; s < 2; ++s) {
            bf16x8 af[8], bfr[4];
#pragma unroll
            for (int m = 0; m < 8; ++m)
                af[m] = *(const bf16x8*)(bA + (aoff[m] ^ (s << 6)));
#pragma unroll
            for (int n = 0; n < 4; ++n)
                bfr[n] = *(const bf16x8*)(bB + (boff[n] ^ (s << 6)));
            __builtin_amdgcn_s_setprio(1);
#pragma unroll
            for (int m = 0; m < 8; ++m)
#pragma unroll
                for (int n = 0; n < 4; ++n)
                    acc[m][n] = __builtin_amdgcn_mfma_f32_16x16x32_bf16(
                        bfr[n], af[m], acc[m][n], 0, 0, 0);
            __builtin_amdgcn_s_setprio(0);
        }
    };

    stage(0);
    for (int i = 0; i < NT - 1; ++i) {
        stage(i + 1);                                   // 16 outstanding
        asm volatile("s_waitcnt vmcnt(8)" ::: "memory");  // tile i landed
        FENCE(); __builtin_amdgcn_s_barrier(); FENCE();
        compute(i);
        FENCE(); __builtin_amdgcn_s_barrier(); FENCE();
    }
    asm volatile("s_waitcnt vmcnt(0)" ::: "memory");
    FENCE(); __builtin_amdgcn_s_barrier(); FENCE();
    compute(NT - 1);

    // epilogue (swapped C/D map, r10..r15-proven): acc[m][n][r]:
    //   src row sr = rowBase + wr*128 + m*16 + (l&15)
    //   tgt col tc = colBase + wc*64 + n*16 + q*4 + r
#pragma unroll
    for (int n = 0; n < 4; ++n) {
        float4 it4 = *(const float4*)&inv_t[colBase + wc * 64 + n * 16 + (q << 2)];
#pragma unroll
        for (int m = 0; m < 8; ++m) {
            float v = acc[m][n][0] * it4.x;
            v = fmaxf(v, acc[m][n][1] * it4.y);
            v = fmaxf(v, acc[m][n][2] * it4.z);
            v = fmaxf(v, acc[m][n][3] * it4.w);
            int row = rowBase + wr * 128 + m * 16 + (l & 15);
            if constexpr (GSH == 3) {   // GW=8: {q,q^1} x r
                v = fmaxf(v, __shfl_xor(v, 16, 64));
                if ((l & 16) == 0) {
                    int g = (colBase >> 3) + wc * 8 + n * 2 + (q >> 1);
                    sbest[(size_t)row * ngroups + g] = v;
                }
            } else {                    // GW=4: fixed q x r, all lanes write
                int g = (colBase >> 2) + wc * 16 + n * 4 + q;
                sbest[(size_t)row * ngroups + g] = v;
            }
        }
    }
}

// --- fused per-row: rowmax + flag + exact f32 refine + gather (1 blk/row) --
// r12-proven block structure (16 candidate cols in flight); v[] widened to 8
// to support ngroups up to 2048 (GW=4 at N=8192).
__global__ __launch_bounds__(256) void flag_refine_kernel(
    const float* __restrict__ sbest, const float* __restrict__ src,
    const float* __restrict__ tgt, const float* __restrict__ inv_t,
    float* __restrict__ out, int ngroups, int gsh) {
    __shared__ __align__(16) float4 s_src[256];
    __shared__ float wmax[4];
    __shared__ int s_slots[MAXSLOTS];
    __shared__ int s_cnt;
    __shared__ float s_wv[4];
    __shared__ int s_wi[4];
    __shared__ int s_best;
    const int row = blockIdx.x;
    const int tid = threadIdx.x;
    const int w = tid >> 6, l = tid & 63;
    const int GW = 1 << gsh;

    s_src[tid] = ((const float4*)(src + (size_t)row * DIM))[tid];
    if (tid == 0) s_cnt = 0;

    // rowmax over groups (nper = ngroups/256, <= 8)
    const float* p = sbest + (size_t)row * ngroups;
    const int nper = ngroups >> 8;
    float v[8];
    float mx = -1e30f;
    for (int j = 0; j < nper; ++j) {
        v[j] = p[tid + j * 256];
        mx = fmaxf(mx, v[j]);
    }
#pragma unroll
    for (int off = 32; off; off >>= 1) mx = fmaxf(mx, __shfl_xor(mx, off, 64));
    if (l == 0) wmax[w] = mx;
    __syncthreads();
    float thr = fmaxf(fmaxf(wmax[0], wmax[1]), fmaxf(wmax[2], wmax[3])) - EPS;
    for (int j = 0; j < nper; ++j) {
        if (v[j] >= thr) {
            int s = atomicAdd(&s_cnt, 1);
            if (s < MAXSLOTS) s_slots[s] = tid + j * 256;
        }
    }
    __syncthreads();

    // exact f32 refine: 16 lanes per candidate column (r6..r15-proven)
    int m = s_cnt;
    if (m > MAXSLOTS) m = MAXSLOTS;
    const int ncand = m << gsh;
    const int grp = tid >> 4;
    const int ln = tid & 15;
    float bv = -1e30f;
    int bi = 0x7fffffff;
    for (int c = grp; c < ncand; c += 16) {
        int col = (s_slots[c >> gsh] << gsh) + (c & (GW - 1));
        const float4* trow = (const float4*)(tgt + (size_t)col * DIM);
        float dot = 0.f;
#pragma unroll
        for (int j = 0; j < 16; ++j) {
            float4 a = s_src[ln + 16 * j];
            float4 b = trow[ln + 16 * j];
            dot = fmaf(a.x, b.x, dot);
            dot = fmaf(a.y, b.y, dot);
            dot = fmaf(a.z, b.z, dot);
            dot = fmaf(a.w, b.w, dot);
        }
        dot += __shfl_xor(dot, 1, 64);
        dot += __shfl_xor(dot, 2, 64);
        dot += __shfl_xor(dot, 4, 64);
        dot += __shfl_xor(dot, 8, 64);
        float vv = dot * inv_t[col];
        if (vv > bv || (vv == bv && col < bi)) { bv = vv; bi = col; }
    }
#pragma unroll
    for (int off = 16; off <= 32; off <<= 1) {
        float v2 = __shfl_xor(bv, off, 64);
        int i2 = __shfl_xor(bi, off, 64);
        if (v2 > bv || (v2 == bv && i2 < bi)) { bv = v2; bi = i2; }
    }
    if (l == 0) { s_wv[w] = bv; s_wi[w] = bi; }
    __syncthreads();
    if (tid == 0) {
        float vv = s_wv[0];
        int ix = s_wi[0];
#pragma unroll
        for (int t = 1; t < 4; ++t) {
            float v2 = s_wv[t];
            int i2 = s_wi[t];
            if (v2 > vv || (v2 == vv && i2 < ix)) { vv = v2; ix = i2; }
        }
        s_best = ix;
    }
    __syncthreads();
    int ixb = s_best;
    ((float4*)(out + (size_t)row * DIM))[tid] =
        ((const float4*)(tgt + (size_t)ixb * DIM))[tid];
}

// ======================= fallback path (round-1, proven) ====================
__global__ void inv_norm_kernel(const float* __restrict__ t,
                                float* __restrict__ inv_t, int n) {
    int wave = (int)((blockIdx.x * blockDim.x + threadIdx.x) >> 6);
    int lane = threadIdx.x & 63;
    if (wave >= n) return;
    const float4* row = (const float4*)(t + (size_t)wave * DIM);
    float ss = 0.f;
#pragma unroll
    for (int p = 0; p < 4; ++p) {
        float4 v = row[lane + 64 * p];
        ss = fmaf(v.x, v.x, ss);
        ss = fmaf(v.y, v.y, ss);
        ss = fmaf(v.z, v.z, ss);
        ss = fmaf(v.w, v.w, ss);
    }
#pragma unroll
    for (int off = 32; off; off >>= 1) ss += __shfl_xor(ss, off, 64);
    if (lane == 0) inv_t[wave] = 1.0f / fmaxf(sqrtf(ss), 1e-12f);
}

__global__ __launch_bounds__(256) void fused_argmax_kernel(
    const float* __restrict__ A, const float* __restrict__ B,
    const float* __restrict__ inv_t, float* __restrict__ sbest,
    int* __restrict__ sidx, int M, int N) {
    __shared__ __align__(16) float sA[32][128 + PAD];
    __shared__ __align__(16) float sB[32][128 + PAD];
    const int tid = threadIdx.x;
    const int tx = tid & 15;
    const int ty = tid >> 4;
    const int rowBase = blockIdx.x * 128;
    const int stripe = blockIdx.y;
    const int stripeN = N / NSTRIPES;
    const int colBase0 = stripe * stripeN;
    const int lr = tid >> 3;
    const int lk = (tid & 7) << 2;
    float best[8];
    int bidx[8];
#pragma unroll
    for (int i = 0; i < 8; ++i) { best[i] = -1e30f; bidx[i] = 0; }
    for (int nt = 0; nt < stripeN / 128; ++nt) {
        const int colBase = colBase0 + nt * 128;
        float acc[8][8];
#pragma unroll
        for (int i = 0; i < 8; ++i)
#pragma unroll
            for (int j = 0; j < 8; ++j) acc[i][j] = 0.f;
        for (int kt = 0; kt < DIM / 32; ++kt) {
            const int k0 = kt * 32;
            __syncthreads();
#pragma unroll
            for (int p = 0; p < 4; ++p) {
                int r = lr + 32 * p;
                float4 va = *(const float4*)(A + (size_t)(rowBase + r) * DIM + k0 + lk);
                sA[lk + 0][r] = va.x; sA[lk + 1][r] = va.y;
                sA[lk + 2][r] = va.z; sA[lk + 3][r] = va.w;
                float4 vb = *(const float4*)(B + (size_t)(colBase + r) * DIM + k0 + lk);
                sB[lk + 0][r] = vb.x; sB[lk + 1][r] = vb.y;
                sB[lk + 2][r] = vb.z; sB[lk + 3][r] = vb.w;
            }
            __syncthreads();
#pragma unroll 4
            for (int k = 0; k < 32; ++k) {
                float4 af0 = *(const float4*)&sA[k][ty * 8];
                float4 af1 = *(const float4*)&sA[k][ty * 8 + 4];
                float4 bf0 = *(const float4*)&sB[k][tx * 8];
                float4 bf1 = *(const float4*)&sB[k][tx * 8 + 4];
                float a[8] = {af0.x, af0.y, af0.z, af0.w, af1.x, af1.y, af1.z, af1.w};
                float b[8] = {bf0.x, bf0.y, bf0.z, bf0.w, bf1.x, bf1.y, bf1.z, bf1.w};
#pragma unroll
                for (int i = 0; i < 8; ++i)
#pragma unroll
                    for (int j = 0; j < 8; ++j)
                        acc[i][j] = fmaf(a[i], b[j], acc[i][j]);
            }
        }
#pragma unroll
        for (int j = 0; j < 8; ++j) {
            int col = colBase + tx * 8 + j;
            float it = inv_t[col];
#pragma unroll
            for (int i = 0; i < 8; ++i) {
                float s = acc[i][j] * it;
                if (s > best[i]) { best[i] = s; bidx[i] = col; }
            }
        }
    }
#pragma unroll
    for (int i = 0; i < 8; ++i) {
        float v = best[i];
        int ix = bidx[i];
#pragma unroll
        for (int off = 1; off < 16; off <<= 1) {
            float v2 = __shfl_xor(v, off, 64);
            int ix2 = __shfl_xor(ix, off, 64);
            if (v2 > v || (v2 == v && ix2 < ix)) { v = v2; ix = ix2; }
        }
        if (tx == 0) {
            int row = rowBase + ty * 8 + i;
            sbest[(size_t)stripe * M + row] = v;
            sidx[(size_t)stripe * M + row] = ix;
        }
    }
}

__global__ void gather_kernel(const float* __restrict__ B,
                              const float* __restrict__ sbest,
                              const int* __restrict__ sidx,
                              float* __restrict__ out, int M) {
    int row = blockIdx.x;
    float v = -1e30f;
    int ix = 0;
#pragma unroll
    for (int s = 0; s < NSTRIPES; ++s) {
        float v2 = sbest[(size_t)s * M + row];
        int ix2 = sidx[(size_t)s * M + row];
        if (v2 > v || (v2 == v && ix2 < ix)) { v = v2; ix = ix2; }
    }
    const float4* srcp = (const float4*)(B + (size_t)ix * DIM);
    float4* dstp = (float4*)(out + (size_t)row * DIM);
    dstp[threadIdx.x] = srcp[threadIdx.x];
}

// ============================================================================
extern "C" void kernel_launch(void* const* d_in, const int* in_sizes, int n_in,
                              void* d_out, int out_size, void* d_ws, size_t ws_size,
                              hipStream_t stream) {
    const float* src = (const float*)d_in[0];
    const float* tgt = (const float*)d_in[1];
    float* out = (float*)d_out;
    int M = in_sizes[0] / DIM;
    int N = in_sizes[1] / DIM;

    auto align256 = [](size_t x) { return (x + 255) & ~(size_t)255; };
    size_t sz_invt = align256((size_t)N * 4);
    size_t sz_bfA = align256((size_t)M * DIM * 2);
    size_t sz_bfB = align256((size_t)N * DIM * 2);
    size_t common = sz_invt + sz_bfA + sz_bfB;
    size_t sz_sbest4 = align256((size_t)M * (N / 4) * 4);
    size_t sz_sbest8 = align256((size_t)M * (N / 8) * 4);

    int gsh = 0;
    if ((M % 256) == 0 && (N % 2048) == 0 && N / 4 <= 2048 &&
        ws_size >= common + sz_sbest4)
        gsh = 2;   // GW=4: halves refine gather traffic
    else if ((M % 256) == 0 && (N % 2048) == 0 && N / 8 <= 1024 &&
             ws_size >= common + sz_sbest8)
        gsh = 3;   // GW=8: r12-proven

    if (gsh) {
        char* p = (char*)d_ws;
        float* inv_t = (float*)p;                 p += sz_invt;
        unsigned short* bfA = (unsigned short*)p; p += sz_bfA;
        unsigned short* bfB = (unsigned short*)p; p += sz_bfB;
        float* sbest = (float*)p;
        int ngroups = N >> gsh;

        convert_all_kernel<<<dim3((M + N + 3) / 4), 256, 0, stream>>>(
            src, tgt, bfA, bfB, inv_t, M, N);
        if (gsh == 2)
            mfma_argmax256_kernel<2><<<dim3(M / 256, N / 256), 512, 0, stream>>>(
                bfA, bfB, inv_t, sbest, M, N);
        else
            mfma_argmax256_kernel<3><<<dim3(M / 256, N / 256), 512, 0, stream>>>(
                bfA, bfB, inv_t, sbest, M, N);
        flag_refine_kernel<<<dim3(M), 256, 0, stream>>>(
            sbest, src, tgt, inv_t, out, ngroups, gsh);
    } else {
        char* ws = (char*)d_ws;
        float* sbest = (float*)ws;
        int* sidx = (int*)(ws + (size_t)NSTRIPES * M * sizeof(float));
        float* inv_t = (float*)(ws + (size_t)NSTRIPES * M * (sizeof(float) + sizeof(int)));
        inv_norm_kernel<<<dim3((N + 3) / 4), 256, 0, stream>>>(tgt, inv_t, N);
        fused_argmax_kernel<<<dim3(M / 128, NSTRIPES), 256, 0, stream>>>(
            src, tgt, inv_t, sbest, sidx, M, N);
        gather_kernel<<<dim3(M), 256, 0, stream>>>(tgt, sbest, sidx, out, M);
    }
}

// Round 17
// 224.640 us; speedup vs baseline: 1.0939x; 1.0939x over previous
//
#include <hip/hip_runtime.h>
#include <math.h>

#define DIM      1024
#define NSTRIPES 16     // fallback path only
#define PAD      4
#define MAXSLOTS 32
// Screen values are dot*inv_t = |src_row| * cos_sim (|src_row| ~ 32): bf16
// screen noise sigma ~= 1.6e-3 in SCREEN units; EPS = 0.08 ~= 35 sigma.
// Verified: rounds 5..16 passed with absmax 0 at this EPS.
#define EPS      0.08f

typedef __attribute__((ext_vector_type(8))) __bf16 bf16x8;
typedef __attribute__((ext_vector_type(4))) __bf16 bf16x4;
typedef __attribute__((ext_vector_type(4))) float f32x4;

#define FENCE() asm volatile("" ::: "memory")

__device__ __forceinline__ void async16(void* lds, const void* g) {
    __builtin_amdgcn_global_load_lds(
        (const __attribute__((address_space(1))) unsigned int*)g,
        (__attribute__((address_space(3))) unsigned int*)lds, 16, 0, 0);
}

// ---- fused: src f32->bf16; tgt f32->bf16 + inverse L2 norm (1 wave/row) ----
// (r14/r15-verified; tgt arithmetic bit-identical to r5..r13 convertB_norm)
__global__ void convert_all_kernel(const float* __restrict__ src,
                                   const float* __restrict__ tgt,
                                   unsigned short* __restrict__ bfA,
                                   unsigned short* __restrict__ bfB,
                                   float* __restrict__ inv_t, int M, int N) {
    int row = blockIdx.x * 4 + (threadIdx.x >> 6);
    int l = threadIdx.x & 63;
    if (row < M) {
        const float4* rp = (const float4*)(src + (size_t)row * DIM);
        unsigned short* wp = bfA + (size_t)row * DIM;
#pragma unroll
        for (int p = 0; p < 2; ++p) {
            int c = l + 64 * p;
            float4 v0 = rp[2 * c], v1 = rp[2 * c + 1];
            bf16x8 o;
            o[0] = (__bf16)v0.x; o[1] = (__bf16)v0.y;
            o[2] = (__bf16)v0.z; o[3] = (__bf16)v0.w;
            o[4] = (__bf16)v1.x; o[5] = (__bf16)v1.y;
            o[6] = (__bf16)v1.z; o[7] = (__bf16)v1.w;
            *(bf16x8*)(wp + (size_t)c * 8) = o;
        }
        return;
    }
    int trow = row - M;
    if (trow >= N) return;
    const float4* rp = (const float4*)(tgt + (size_t)trow * DIM);
    unsigned short* wp = bfB + (size_t)trow * DIM;
    float ss = 0.f;
#pragma unroll
    for (int p = 0; p < 4; ++p) {
        float4 v = rp[l + 64 * p];
        bf16x4 o;
        o[0] = (__bf16)v.x; o[1] = (__bf16)v.y;
        o[2] = (__bf16)v.z; o[3] = (__bf16)v.w;
        *(bf16x4*)(wp + (size_t)(l + 64 * p) * 4) = o;
        ss = fmaf(v.x, v.x, ss);
        ss = fmaf(v.y, v.y, ss);
        ss = fmaf(v.z, v.z, ss);
        ss = fmaf(v.w, v.w, ss);
    }
#pragma unroll
    for (int off = 32; off; off >>= 1) ss += __shfl_xor(ss, off, 64);
    if (l == 0) inv_t[trow] = 1.0f / fmaxf(sqrtf(ss), 1e-12f);
}

// ---- 256x256-tile bf16 MFMA screen, BK=64, ring-2, counted-vmcnt ----------
// r12 structure VERBATIM (proven 156us, absmax 0, 0 bank conflicts, GW=8).
// r13 (phase-split), r14 (T1 swizzle), r16 (GW=4) all A/B-regressed; this is
// the best-measured configuration of this algorithm.
__global__ __launch_bounds__(512) void mfma_argmax256_kernel(
    const unsigned short* __restrict__ Abf,
    const unsigned short* __restrict__ Bbf,
    const float* __restrict__ inv_t,
    float* __restrict__ sbest,   // [M][N/8]
    int M, int N) {
    __shared__ __align__(16) unsigned short sA[2][16384];
    __shared__ __align__(16) unsigned short sB[2][16384];
    const int tid = threadIdx.x;
    const int w = tid >> 6, l = tid & 63;
    const int wr = w >> 2, wc = w & 3;   // 2 x 4 wave grid
    const int rowBase = blockIdx.x * 256;
    const int colBase = blockIdx.y * 256;
    const int ngroups = N >> 3;
    const int NT = DIM / 64;

    int goff[4], lbase[4];
#pragma unroll
    for (int j = 0; j < 4; ++j) {
        int c = j * 512 + tid;
        int row = c >> 3, c8 = c & 7;
        goff[j] = row * DIM + (c8 ^ (row & 7)) * 8;  // ushort units
        lbase[j] = (j * 512 + w * 64) * 8;           // wave-uniform (ushort)
    }

    const int q = l >> 4;
    int aoff[8], boff[4];
#pragma unroll
    for (int m = 0; m < 8; ++m) {
        int row = wr * 128 + m * 16 + (l & 15);
        aoff[m] = (row * 128 + q * 16) ^ ((row & 7) << 4);
    }
#pragma unroll
    for (int n = 0; n < 4; ++n) {
        int col = wc * 64 + n * 16 + (l & 15);
        boff[n] = (col * 128 + q * 16) ^ ((col & 7) << 4);
    }

    f32x4 acc[8][4];
#pragma unroll
    for (int m = 0; m < 8; ++m)
#pragma unroll
        for (int n = 0; n < 4; ++n) acc[m][n] = (f32x4){0.f, 0.f, 0.f, 0.f};

    const unsigned short* ga = Abf + (size_t)rowBase * DIM;
    const unsigned short* gb = Bbf + (size_t)colBase * DIM;

    auto stage = [&](int t) {
        unsigned short* dA = &sA[t & 1][0];
        unsigned short* dB = &sB[t & 1][0];
#pragma unroll
        for (int j = 0; j < 4; ++j) {
            async16(dA + lbase[j], ga + t * 64 + goff[j]);
            async16(dB + lbase[j], gb + t * 64 + goff[j]);
        }
    };
    auto compute = [&](int i) {
        const char* bA = (const char*)&sA[i & 1][0];
        const char* bB = (const char*)&sB[i & 1][0];
#pragma unroll
        for (int s = 0; s < 2; ++s) {
            bf16x8 af[8], bfr[4];
#pragma unroll
            for (int m = 0; m < 8; ++m)
                af[m] = *(const bf16x8*)(bA + (aoff[m] ^ (s << 6)));
#pragma unroll
            for (int n = 0; n < 4; ++n)
                bfr[n] = *(const bf16x8*)(bB + (boff[n] ^ (s << 6)));
            __builtin_amdgcn_s_setprio(1);
#pragma unroll
            for (int m = 0; m < 8; ++m)
#pragma unroll
                for (int n = 0; n < 4; ++n)
                    acc[m][n] = __builtin_amdgcn_mfma_f32_16x16x32_bf16(
                        bfr[n], af[m], acc[m][n], 0, 0, 0);
            __builtin_amdgcn_s_setprio(0);
        }
    };

    stage(0);
    for (int i = 0; i < NT - 1; ++i) {
        stage(i + 1);                                   // 16 outstanding
        asm volatile("s_waitcnt vmcnt(8)" ::: "memory");  // tile i landed
        FENCE(); __builtin_amdgcn_s_barrier(); FENCE();
        compute(i);
        FENCE(); __builtin_amdgcn_s_barrier(); FENCE();
    }
    asm volatile("s_waitcnt vmcnt(0)" ::: "memory");
    FENCE(); __builtin_amdgcn_s_barrier(); FENCE();
    compute(NT - 1);

    // epilogue (swapped C/D map, GW=8, r10..r15-proven): acc[m][n][r]:
    //   src row sr = rowBase + wr*128 + m*16 + (l&15)
    //   tgt col tc = colBase + wc*64 + n*16 + q*4 + r
    // group = 8 cols: {q,q^1} x r  ->  g = wc*8 + n*2 + (q>>1)
#pragma unroll
    for (int n = 0; n < 4; ++n) {
        float4 it4 = *(const float4*)&inv_t[colBase + wc * 64 + n * 16 + (q << 2)];
#pragma unroll
        for (int m = 0; m < 8; ++m) {
            float v = acc[m][n][0] * it4.x;
            v = fmaxf(v, acc[m][n][1] * it4.y);
            v = fmaxf(v, acc[m][n][2] * it4.z);
            v = fmaxf(v, acc[m][n][3] * it4.w);
            v = fmaxf(v, __shfl_xor(v, 16, 64));
            if ((l & 16) == 0) {
                int row = rowBase + wr * 128 + m * 16 + (l & 15);
                int g = (colBase >> 3) + wc * 8 + n * 2 + (q >> 1);
                sbest[(size_t)row * ngroups + g] = v;
            }
        }
    }
}

// --- fused per-row: rowmax + flag + exact f32 refine + gather (1 blk/row) --
// r12-proven block structure (16 candidate cols in flight).
__global__ __launch_bounds__(256) void flag_refine_kernel(
    const float* __restrict__ sbest, const float* __restrict__ src,
    const float* __restrict__ tgt, const float* __restrict__ inv_t,
    float* __restrict__ out, int ngroups, int gsh) {
    __shared__ __align__(16) float4 s_src[256];
    __shared__ float wmax[4];
    __shared__ int s_slots[MAXSLOTS];
    __shared__ int s_cnt;
    __shared__ float s_wv[4];
    __shared__ int s_wi[4];
    __shared__ int s_best;
    const int row = blockIdx.x;
    const int tid = threadIdx.x;
    const int w = tid >> 6, l = tid & 63;
    const int GW = 1 << gsh;

    s_src[tid] = ((const float4*)(src + (size_t)row * DIM))[tid];
    if (tid == 0) s_cnt = 0;

    // rowmax over groups (nper = ngroups/256, <= 8)
    const float* p = sbest + (size_t)row * ngroups;
    const int nper = ngroups >> 8;
    float v[8];
    float mx = -1e30f;
    for (int j = 0; j < nper; ++j) {
        v[j] = p[tid + j * 256];
        mx = fmaxf(mx, v[j]);
    }
#pragma unroll
    for (int off = 32; off; off >>= 1) mx = fmaxf(mx, __shfl_xor(mx, off, 64));
    if (l == 0) wmax[w] = mx;
    __syncthreads();
    float thr = fmaxf(fmaxf(wmax[0], wmax[1]), fmaxf(wmax[2], wmax[3])) - EPS;
    for (int j = 0; j < nper; ++j) {
        if (v[j] >= thr) {
            int s = atomicAdd(&s_cnt, 1);
            if (s < MAXSLOTS) s_slots[s] = tid + j * 256;
        }
    }
    __syncthreads();

    // exact f32 refine: 16 lanes per candidate column (r6..r16-proven)
    int m = s_cnt;
    if (m > MAXSLOTS) m = MAXSLOTS;
    const int ncand = m << gsh;
    const int grp = tid >> 4;
    const int ln = tid & 15;
    float bv = -1e30f;
    int bi = 0x7fffffff;
    for (int c = grp; c < ncand; c += 16) {
        int col = (s_slots[c >> gsh] << gsh) + (c & (GW - 1));
        const float4* trow = (const float4*)(tgt + (size_t)col * DIM);
        float dot = 0.f;
#pragma unroll
        for (int j = 0; j < 16; ++j) {
            float4 a = s_src[ln + 16 * j];
            float4 b = trow[ln + 16 * j];
            dot = fmaf(a.x, b.x, dot);
            dot = fmaf(a.y, b.y, dot);
            dot = fmaf(a.z, b.z, dot);
            dot = fmaf(a.w, b.w, dot);
        }
        dot += __shfl_xor(dot, 1, 64);
        dot += __shfl_xor(dot, 2, 64);
        dot += __shfl_xor(dot, 4, 64);
        dot += __shfl_xor(dot, 8, 64);
        float vv = dot * inv_t[col];
        if (vv > bv || (vv == bv && col < bi)) { bv = vv; bi = col; }
    }
#pragma unroll
    for (int off = 16; off <= 32; off <<= 1) {
        float v2 = __shfl_xor(bv, off, 64);
        int i2 = __shfl_xor(bi, off, 64);
        if (v2 > bv || (v2 == bv && i2 < bi)) { bv = v2; bi = i2; }
    }
    if (l == 0) { s_wv[w] = bv; s_wi[w] = bi; }
    __syncthreads();
    if (tid == 0) {
        float vv = s_wv[0];
        int ix = s_wi[0];
#pragma unroll
        for (int t = 1; t < 4; ++t) {
            float v2 = s_wv[t];
            int i2 = s_wi[t];
            if (v2 > vv || (v2 == vv && i2 < ix)) { vv = v2; ix = i2; }
        }
        s_best = ix;
    }
    __syncthreads();
    int ixb = s_best;
    ((float4*)(out + (size_t)row * DIM))[tid] =
        ((const float4*)(tgt + (size_t)ixb * DIM))[tid];
}

// ======================= fallback path (round-1, proven) ====================
__global__ void inv_norm_kernel(const float* __restrict__ t,
                                float* __restrict__ inv_t, int n) {
    int wave = (int)((blockIdx.x * blockDim.x + threadIdx.x) >> 6);
    int lane = threadIdx.x & 63;
    if (wave >= n) return;
    const float4* row = (const float4*)(t + (size_t)wave * DIM);
    float ss = 0.f;
#pragma unroll
    for (int p = 0; p < 4; ++p) {
        float4 v = row[lane + 64 * p];
        ss = fmaf(v.x, v.x, ss);
        ss = fmaf(v.y, v.y, ss);
        ss = fmaf(v.z, v.z, ss);
        ss = fmaf(v.w, v.w, ss);
    }
#pragma unroll
    for (int off = 32; off; off >>= 1) ss += __shfl_xor(ss, off, 64);
    if (lane == 0) inv_t[wave] = 1.0f / fmaxf(sqrtf(ss), 1e-12f);
}

__global__ __launch_bounds__(256) void fused_argmax_kernel(
    const float* __restrict__ A, const float* __restrict__ B,
    const float* __restrict__ inv_t, float* __restrict__ sbest,
    int* __restrict__ sidx, int M, int N) {
    __shared__ __align__(16) float sA[32][128 + PAD];
    __shared__ __align__(16) float sB[32][128 + PAD];
    const int tid = threadIdx.x;
    const int tx = tid & 15;
    const int ty = tid >> 4;
    const int rowBase = blockIdx.x * 128;
    const int stripe = blockIdx.y;
    const int stripeN = N / NSTRIPES;
    const int colBase0 = stripe * stripeN;
    const int lr = tid >> 3;
    const int lk = (tid & 7) << 2;
    float best[8];
    int bidx[8];
#pragma unroll
    for (int i = 0; i < 8; ++i) { best[i] = -1e30f; bidx[i] = 0; }
    for (int nt = 0; nt < stripeN / 128; ++nt) {
        const int colBase = colBase0 + nt * 128;
        float acc[8][8];
#pragma unroll
        for (int i = 0; i < 8; ++i)
#pragma unroll
            for (int j = 0; j < 8; ++j) acc[i][j] = 0.f;
        for (int kt = 0; kt < DIM / 32; ++kt) {
            const int k0 = kt * 32;
            __syncthreads();
#pragma unroll
            for (int p = 0; p < 4; ++p) {
                int r = lr + 32 * p;
                float4 va = *(const float4*)(A + (size_t)(rowBase + r) * DIM + k0 + lk);
                sA[lk + 0][r] = va.x; sA[lk + 1][r] = va.y;
                sA[lk + 2][r] = va.z; sA[lk + 3][r] = va.w;
                float4 vb = *(const float4*)(B + (size_t)(colBase + r) * DIM + k0 + lk);
                sB[lk + 0][r] = vb.x; sB[lk + 1][r] = vb.y;
                sB[lk + 2][r] = vb.z; sB[lk + 3][r] = vb.w;
            }
            __syncthreads();
#pragma unroll 4
            for (int k = 0; k < 32; ++k) {
                float4 af0 = *(const float4*)&sA[k][ty * 8];
                float4 af1 = *(const float4*)&sA[k][ty * 8 + 4];
                float4 bf0 = *(const float4*)&sB[k][tx * 8];
                float4 bf1 = *(const float4*)&sB[k][tx * 8 + 4];
                float a[8] = {af0.x, af0.y, af0.z, af0.w, af1.x, af1.y, af1.z, af1.w};
                float b[8] = {bf0.x, bf0.y, bf0.z, bf0.w, bf1.x, bf1.y, bf1.z, bf1.w};
#pragma unroll
                for (int i = 0; i < 8; ++i)
#pragma unroll
                    for (int j = 0; j < 8; ++j)
                        acc[i][j] = fmaf(a[i], b[j], acc[i][j]);
            }
        }
#pragma unroll
        for (int j = 0; j < 8; ++j) {
            int col = colBase + tx * 8 + j;
            float it = inv_t[col];
#pragma unroll
            for (int i = 0; i < 8; ++i) {
                float s = acc[i][j] * it;
                if (s > best[i]) { best[i] = s; bidx[i] = col; }
            }
        }
    }
#pragma unroll
    for (int i = 0; i < 8; ++i) {
        float v = best[i];
        int ix = bidx[i];
#pragma unroll
        for (int off = 1; off < 16; off <<= 1) {
            float v2 = __shfl_xor(v, off, 64);
            int ix2 = __shfl_xor(ix, off, 64);
            if (v2 > v || (v2 == v && ix2 < ix)) { v = v2; ix = ix2; }
        }
        if (tx == 0) {
            int row = rowBase + ty * 8 + i;
            sbest[(size_t)stripe * M + row] = v;
            sidx[(size_t)stripe * M + row] = ix;
        }
    }
}

__global__ void gather_kernel(const float* __restrict__ B,
                              const float* __restrict__ sbest,
                              const int* __restrict__ sidx,
                              float* __restrict__ out, int M) {
    int row = blockIdx.x;
    float v = -1e30f;
    int ix = 0;
#pragma unroll
    for (int s = 0; s < NSTRIPES; ++s) {
        float v2 = sbest[(size_t)s * M + row];
        int ix2 = sidx[(size_t)s * M + row];
        if (v2 > v || (v2 == v && ix2 < ix)) { v = v2; ix = ix2; }
    }
    const float4* srcp = (const float4*)(B + (size_t)ix * DIM);
    float4* dstp = (float4*)(out + (size_t)row * DIM);
    dstp[threadIdx.x] = srcp[threadIdx.x];
}

// ============================================================================
extern "C" void kernel_launch(void* const* d_in, const int* in_sizes, int n_in,
                              void* d_out, int out_size, void* d_ws, size_t ws_size,
                              hipStream_t stream) {
    const float* src = (const float*)d_in[0];
    const float* tgt = (const float*)d_in[1];
    float* out = (float*)d_out;
    int M = in_sizes[0] / DIM;
    int N = in_sizes[1] / DIM;

    auto align256 = [](size_t x) { return (x + 255) & ~(size_t)255; };
    size_t sz_invt = align256((size_t)N * 4);
    size_t sz_bfA = align256((size_t)M * DIM * 2);
    size_t sz_bfB = align256((size_t)N * DIM * 2);
    size_t common = sz_invt + sz_bfA + sz_bfB;
    size_t sz_sbest8 = align256((size_t)M * (N / 8) * 4);

    if ((M % 256) == 0 && (N % 2048) == 0 && N / 8 <= 2048 &&
        ws_size >= common + sz_sbest8) {
        char* p = (char*)d_ws;
        float* inv_t = (float*)p;                 p += sz_invt;
        unsigned short* bfA = (unsigned short*)p; p += sz_bfA;
        unsigned short* bfB = (unsigned short*)p; p += sz_bfB;
        float* sbest = (float*)p;
        int ngroups = N >> 3;

        convert_all_kernel<<<dim3((M + N + 3) / 4), 256, 0, stream>>>(
            src, tgt, bfA, bfB, inv_t, M, N);
        mfma_argmax256_kernel<<<dim3(M / 256, N / 256), 512, 0, stream>>>(
            bfA, bfB, inv_t, sbest, M, N);
        flag_refine_kernel<<<dim3(M), 256, 0, stream>>>(
            sbest, src, tgt, inv_t, out, ngroups, 3);
    } else {
        char* ws = (char*)d_ws;
        float* sbest = (float*)ws;
        int* sidx = (int*)(ws + (size_t)NSTRIPES * M * sizeof(float));
        float* inv_t = (float*)(ws + (size_t)NSTRIPES * M * (sizeof(float) + sizeof(int)));
        inv_norm_kernel<<<dim3((N + 3) / 4), 256, 0, stream>>>(tgt, inv_t, N);
        fused_argmax_kernel<<<dim3(M / 128, NSTRIPES), 256, 0, stream>>>(
            src, tgt, inv_t, sbest, sidx, M, N);
        gather_kernel<<<dim3(M), 256, 0, stream>>>(tgt, sbest, sidx, out, M);
    }
}